// Round 8
// baseline (576.935 us; speedup 1.0000x reference)
//
#include <hip/hip_runtime.h>
#include <hip/hip_fp16.h>
#include <hip/hip_cooperative_groups.h>

namespace cg = cooperative_groups;

#define B_DIM 64

__device__ __forceinline__ float fast_rcp(float x) {
#if __has_builtin(__builtin_amdgcn_rcpf)
    return __builtin_amdgcn_rcpf(x);
#else
    return 1.0f / x;
#endif
}

__device__ __forceinline__ float wave_sum(float x) {
    #pragma unroll
    for (int off = 1; off < 64; off <<= 1) x += __shfl_xor(x, off);
    return x;
}

// ================= cooperative single-kernel path =================
// Sinkhorn, linear space, E = exp(s) held ENTIRELY in registers.
// grid 512 x 512 (2 blocks/CU, co-resident). Block g: batch b = g>>3,
// row slice half = g&7 -> rows [half*64, half*64+64) (2 chunks of 32).
// Wave w owns rows half*64 + q*32 + 4w..4w+3 (q=0,1); lane l owns cols
// {j*256 + 4l .. +3 : j=0..3} (float4-coalesced in s, cs and out).
// Per thread: 128 E elements as 16 float4 of packed fp16 (64 VGPRs).
// 5 epochs of {row-step (regs), col partials (regs) -> LDS[8][1024]
// reduce -> atomicAdd cs} separated by grid.sync(); then out from regs.
// cs rotation cs0->cs1->cs2->cs0->cs1; epoch e zeroes cs[(e+1)%3]
// (idle that epoch); cs0 pre-zeroed by hipMemsetAsync.

__global__ __launch_bounds__(512, 4) void sinkhorn_coop(
    const float* __restrict__ s, const int* __restrict__ nrows,
    const int* __restrict__ ncols, float* __restrict__ cs0,
    float* __restrict__ cs1, float* __restrict__ cs2,
    float* __restrict__ out)
{
    cg::grid_group grid = cg::this_grid();
    __shared__ float cls[8 * 1024];   // 32 KiB

    const int g = blockIdx.x;
    const int b = g >> 3;
    const int half = g & 7;
    const int t = threadIdx.x;
    const int w = t >> 6;
    const int l = t & 63;
    const int c4 = l << 2;
    const int nr = nrows[b];
    const int nc = ncols[b];
    const int rbase = (half << 6) + (w << 2);   // + q*32 + rw

    float4 eA[2][4], eB[2][4];   // packed fp16: eA = cols j0,j1; eB = j2,j3
    float aR[2][4];

    // epoch-0 region: zero cs1 (epoch-1 target). cs0 pre-zeroed on host.
    if (t < 128) cs1[(b << 10) + (half << 7) + t] = 0.f;

    // ---- epoch 0 row-step: load s, exp, pack, row sums (w = 1) ----
    #pragma unroll
    for (int q = 0; q < 2; ++q) {
        #pragma unroll
        for (int rw = 0; rw < 4; ++rw) {
            const int r = rbase + (q << 5) + rw;
            float e[16];
            if (r < nr) {   // wave-uniform
                const float* __restrict__ srow =
                    s + ((size_t)b << 20) + ((size_t)r << 10);
                // j = 0,1: cols <= 511 < nc (nc >= 512) -> unguarded
                const float4 x0 = *reinterpret_cast<const float4*>(srow + c4);
                const float4 x1 = *reinterpret_cast<const float4*>(srow + 256 + c4);
                e[0] = __expf(x0.x); e[1] = __expf(x0.y);
                e[2] = __expf(x0.z); e[3] = __expf(x0.w);
                e[4] = __expf(x1.x); e[5] = __expf(x1.y);
                e[6] = __expf(x1.z); e[7] = __expf(x1.w);
                #pragma unroll
                for (int j = 2; j < 4; ++j) {
                    const int c = (j << 8) + c4;
                    if (c < nc) {
                        const float4 x = *reinterpret_cast<const float4*>(srow + c);
                        e[j*4+0] = __expf(x.x);
                        e[j*4+1] = (c + 1 < nc) ? __expf(x.y) : 0.f;
                        e[j*4+2] = (c + 2 < nc) ? __expf(x.z) : 0.f;
                        e[j*4+3] = (c + 3 < nc) ? __expf(x.w) : 0.f;
                    } else {
                        e[j*4+0] = 0.f; e[j*4+1] = 0.f;
                        e[j*4+2] = 0.f; e[j*4+3] = 0.f;
                    }
                }
            } else {
                #pragma unroll
                for (int i = 0; i < 16; ++i) e[i] = 0.f;
            }
            __half2 h[8];
            #pragma unroll
            for (int k = 0; k < 8; ++k)
                h[k] = __floats2half2_rn(e[2*k], e[2*k+1]);
            eA[q][rw] = *reinterpret_cast<const float4*>(&h[0]);
            eB[q][rw] = *reinterpret_cast<const float4*>(&h[4]);
            float acc = 0.f;
            #pragma unroll
            for (int i = 0; i < 16; ++i) acc += e[i];
            acc = wave_sum(acc);
            aR[q][rw] = (r < nr) ? fast_rcp(acc) : 0.f;
        }
    }

    // ---- shared col phase: partials -> LDS -> reduce -> atomics ----
    auto col_phase = [&](float* __restrict__ cscur) {
        float4 p[4];
        p[0] = make_float4(0.f, 0.f, 0.f, 0.f); p[1] = p[0];
        p[2] = p[0]; p[3] = p[0];
        #pragma unroll
        for (int q = 0; q < 2; ++q) {
            #pragma unroll
            for (int rw = 0; rw < 4; ++rw) {
                const float av = aR[q][rw];
                const __half2* hA = reinterpret_cast<const __half2*>(&eA[q][rw]);
                const __half2* hB = reinterpret_cast<const __half2*>(&eB[q][rw]);
                float2 f;
                f = __half22float2(hA[0]); p[0].x = fmaf(f.x, av, p[0].x); p[0].y = fmaf(f.y, av, p[0].y);
                f = __half22float2(hA[1]); p[0].z = fmaf(f.x, av, p[0].z); p[0].w = fmaf(f.y, av, p[0].w);
                f = __half22float2(hA[2]); p[1].x = fmaf(f.x, av, p[1].x); p[1].y = fmaf(f.y, av, p[1].y);
                f = __half22float2(hA[3]); p[1].z = fmaf(f.x, av, p[1].z); p[1].w = fmaf(f.y, av, p[1].w);
                f = __half22float2(hB[0]); p[2].x = fmaf(f.x, av, p[2].x); p[2].y = fmaf(f.y, av, p[2].y);
                f = __half22float2(hB[1]); p[2].z = fmaf(f.x, av, p[2].z); p[2].w = fmaf(f.y, av, p[2].w);
                f = __half22float2(hB[2]); p[3].x = fmaf(f.x, av, p[3].x); p[3].y = fmaf(f.y, av, p[3].y);
                f = __half22float2(hB[3]); p[3].z = fmaf(f.x, av, p[3].z); p[3].w = fmaf(f.y, av, p[3].w);
            }
        }
        #pragma unroll
        for (int j = 0; j < 4; ++j)
            *reinterpret_cast<float4*>(cls + (w << 10) + (j << 8) + c4) = p[j];
        __syncthreads();
        float* __restrict__ cur = cscur + (b << 10);
        #pragma unroll
        for (int hh = 0; hh < 2; ++hh) {
            const int c = t + (hh << 9);
            float v = 0.f;
            #pragma unroll
            for (int ww = 0; ww < 8; ++ww) v += cls[(ww << 10) + c];
            if (v != 0.f) atomicAdd(cur + c, v);
        }
    };

    // ---- shared row phase (epochs >= 1): w = 1/cs_prev, from registers ----
    auto row_phase = [&](const float* __restrict__ csprev) {
        float4 wv[4];
        const float* __restrict__ csb = csprev + (b << 10);
        #pragma unroll
        for (int j = 0; j < 4; ++j) {
            const int c = (j << 8) + c4;
            const float4 v = *reinterpret_cast<const float4*>(csb + c);
            wv[j].x = (c + 0 < nc) ? fast_rcp(v.x) : 0.f;
            wv[j].y = (c + 1 < nc) ? fast_rcp(v.y) : 0.f;
            wv[j].z = (c + 2 < nc) ? fast_rcp(v.z) : 0.f;
            wv[j].w = (c + 3 < nc) ? fast_rcp(v.w) : 0.f;
        }
        #pragma unroll
        for (int q = 0; q < 2; ++q) {
            #pragma unroll
            for (int rw = 0; rw < 4; ++rw) {
                const int r = rbase + (q << 5) + rw;
                const __half2* hA = reinterpret_cast<const __half2*>(&eA[q][rw]);
                const __half2* hB = reinterpret_cast<const __half2*>(&eB[q][rw]);
                float2 f;
                float a0, a1;
                f = __half22float2(hA[0]); a0 = f.x * wv[0].x;            a1 = f.y * wv[0].y;
                f = __half22float2(hA[1]); a0 = fmaf(f.x, wv[0].z, a0);   a1 = fmaf(f.y, wv[0].w, a1);
                f = __half22float2(hA[2]); a0 = fmaf(f.x, wv[1].x, a0);   a1 = fmaf(f.y, wv[1].y, a1);
                f = __half22float2(hA[3]); a0 = fmaf(f.x, wv[1].z, a0);   a1 = fmaf(f.y, wv[1].w, a1);
                f = __half22float2(hB[0]); a0 = fmaf(f.x, wv[2].x, a0);   a1 = fmaf(f.y, wv[2].y, a1);
                f = __half22float2(hB[1]); a0 = fmaf(f.x, wv[2].z, a0);   a1 = fmaf(f.y, wv[2].w, a1);
                f = __half22float2(hB[2]); a0 = fmaf(f.x, wv[3].x, a0);   a1 = fmaf(f.y, wv[3].y, a1);
                f = __half22float2(hB[3]); a0 = fmaf(f.x, wv[3].z, a0);   a1 = fmaf(f.y, wv[3].w, a1);
                const float sum = wave_sum(a0 + a1);
                aR[q][rw] = (r < nr) ? fast_rcp(sum) : 0.f;
            }
        }
    };

    col_phase(cs0);  grid.sync();                               // epoch 0
    if (t < 128) cs2[(b << 10) + (half << 7) + t] = 0.f;        // for epoch 2
    row_phase(cs0);  col_phase(cs1);  grid.sync();              // epoch 1
    if (t < 128) cs0[(b << 10) + (half << 7) + t] = 0.f;        // for epoch 3
    row_phase(cs1);  col_phase(cs2);  grid.sync();              // epoch 2
    if (t < 128) cs1[(b << 10) + (half << 7) + t] = 0.f;        // for epoch 4
    row_phase(cs2);  col_phase(cs0);  grid.sync();              // epoch 3
    row_phase(cs0);  col_phase(cs1);  grid.sync();              // epoch 4

    // ---- output: out = E * a[r] / cs1[c], plus zero-fill rows 512.. ----
    {
        float4 wv[4];
        const float* __restrict__ csb = cs1 + (b << 10);
        #pragma unroll
        for (int j = 0; j < 4; ++j) {
            const int c = (j << 8) + c4;
            const float4 v = *reinterpret_cast<const float4*>(csb + c);
            wv[j].x = (c + 0 < nc) ? fast_rcp(v.x) : 0.f;
            wv[j].y = (c + 1 < nc) ? fast_rcp(v.y) : 0.f;
            wv[j].z = (c + 2 < nc) ? fast_rcp(v.z) : 0.f;
            wv[j].w = (c + 3 < nc) ? fast_rcp(v.w) : 0.f;
        }
        #pragma unroll
        for (int q = 0; q < 2; ++q) {
            #pragma unroll
            for (int rw = 0; rw < 4; ++rw) {
                const int r = rbase + (q << 5) + rw;
                const float av = aR[q][rw];   // 0 for invalid rows -> zeros
                float* __restrict__ orow =
                    out + ((size_t)b << 20) + ((size_t)r << 10);
                const __half2* hA = reinterpret_cast<const __half2*>(&eA[q][rw]);
                const __half2* hB = reinterpret_cast<const __half2*>(&eB[q][rw]);
                float2 fa, fb;
                float4 o;
                fa = __half22float2(hA[0]); fb = __half22float2(hA[1]);
                o = make_float4(fa.x*av*wv[0].x, fa.y*av*wv[0].y,
                                fb.x*av*wv[0].z, fb.y*av*wv[0].w);
                *reinterpret_cast<float4*>(orow + c4) = o;
                fa = __half22float2(hA[2]); fb = __half22float2(hA[3]);
                o = make_float4(fa.x*av*wv[1].x, fa.y*av*wv[1].y,
                                fb.x*av*wv[1].z, fb.y*av*wv[1].w);
                *reinterpret_cast<float4*>(orow + 256 + c4) = o;
                fa = __half22float2(hB[0]); fb = __half22float2(hB[1]);
                o = make_float4(fa.x*av*wv[2].x, fa.y*av*wv[2].y,
                                fb.x*av*wv[2].z, fb.y*av*wv[2].w);
                *reinterpret_cast<float4*>(orow + 512 + c4) = o;
                fa = __half22float2(hB[2]); fb = __half22float2(hB[3]);
                o = make_float4(fa.x*av*wv[3].x, fa.y*av*wv[3].y,
                                fb.x*av*wv[3].z, fb.y*av*wv[3].w);
                *reinterpret_cast<float4*>(orow + 768 + c4) = o;
            }
        }
        // rows 512..1023 of this batch: block's 64-row zero slice
        const float4 z = make_float4(0.f, 0.f, 0.f, 0.f);
        float4* __restrict__ zbase = reinterpret_cast<float4*>(
            out + ((size_t)b << 20) + ((size_t)(512 + (half << 6)) << 10));
        #pragma unroll 4
        for (int idx = t; idx < 64 * 256; idx += 512)
            zbase[idx] = z;
    }
}

// ==================== round-7 fallback (coop launch failure) ===============

#define RCH 32

__device__ __forceinline__ void phase2_col(
    const __half* __restrict__ e_lds, const float* __restrict__ a_lds,
    int b, int nc, int t, float* __restrict__ cs_cur)
{
    const int c0 = t << 1;
    if (c0 >= nc) return;
    float s0 = 0.f, s1 = 0.f;
    #pragma unroll
    for (int rr = 0; rr < RCH; ++rr) {
        const float2 f = __half22float2(
            *reinterpret_cast<const __half2*>(e_lds + (rr << 10) + c0));
        const float av = a_lds[rr];
        s0 = fmaf(f.x, av, s0);
        s1 = fmaf(f.y, av, s1);
    }
    if (s0 != 0.f) atomicAdd(cs_cur + (b << 10) + c0, s0);
    if (s1 != 0.f) atomicAdd(cs_cur + (b << 10) + c0 + 1, s1);
}

__device__ __forceinline__ void decode_pair_bid(int bid, int& b, int& rc) {
    const int xcd = bid & 7;
    const int j = bid >> 3;
    rc = j & 15;
    b = (xcd << 3) | (j >> 4);
}

__global__ __launch_bounds__(512) void pair_first(
    const float* __restrict__ s, const int* __restrict__ nrows,
    const int* __restrict__ ncols, __half* __restrict__ E,
    float* __restrict__ a, float* __restrict__ cs_cur,
    float* __restrict__ cs_next)
{
    int b, rc;
    decode_pair_bid(blockIdx.x, b, rc);
    const int t = threadIdx.x;
    if (t < 64) cs_next[(b << 10) + (rc << 6) + t] = 0.f;

    const int nr = nrows[b];
    const int r0 = rc << 5;
    if (r0 >= nr) return;
    const int nc = ncols[b];

    __shared__ __half e_lds[RCH * 1024];
    __shared__ float a_lds[RCH];

    const int wave = t >> 6;
    const int lane = t & 63;
    const int cbase = lane << 4;
    const bool cOK = cbase < nc;

    #pragma unroll 1
    for (int k = 0; k < 4; ++k) {
        const int rr = (wave << 2) + k;
        const int r = r0 + rr;
        float sum = 0.f;
        __half2 h[8];
        if (r < nr && cOK) {
            const float* __restrict__ srow =
                s + ((size_t)b << 20) + ((size_t)r << 10) + cbase;
            float e[16];
            #pragma unroll
            for (int q = 0; q < 4; ++q) {
                const float4 x = *reinterpret_cast<const float4*>(srow + (q << 2));
                e[4*q+0] = __expf(x.x); e[4*q+1] = __expf(x.y);
                e[4*q+2] = __expf(x.z); e[4*q+3] = __expf(x.w);
            }
            #pragma unroll
            for (int j = 0; j < 16; ++j)
                if (cbase + j >= nc) e[j] = 0.f;
            #pragma unroll
            for (int q = 0; q < 8; ++q)
                h[q] = __floats2half2_rn(e[2*q], e[2*q+1]);
            __half* __restrict__ erow =
                E + ((size_t)b << 19) + ((size_t)r << 10) + cbase;
            *reinterpret_cast<float4*>(erow)     = *reinterpret_cast<const float4*>(&h[0]);
            *reinterpret_cast<float4*>(erow + 8) = *reinterpret_cast<const float4*>(&h[4]);
            #pragma unroll
            for (int j = 0; j < 16; ++j) sum += e[j];
        } else {
            #pragma unroll
            for (int q = 0; q < 8; ++q) h[q] = __floats2half2_rn(0.f, 0.f);
        }
        __half* dst = e_lds + (rr << 10) + cbase;
        *reinterpret_cast<float4*>(dst)     = *reinterpret_cast<const float4*>(&h[0]);
        *reinterpret_cast<float4*>(dst + 8) = *reinterpret_cast<const float4*>(&h[4]);
        sum = wave_sum(sum);
        if (lane == 0) a_lds[rr] = (r < nr) ? 1.0f / sum : 0.f;
    }
    __syncthreads();
    if (t < RCH) a[(b << 9) + r0 + t] = a_lds[t];

    phase2_col(e_lds, a_lds, b, nc, t, cs_cur);
}

__global__ __launch_bounds__(512) void pair_mid(
    const __half* __restrict__ E, const int* __restrict__ nrows,
    const int* __restrict__ ncols, const float* __restrict__ cs_prev,
    float* __restrict__ a, float* __restrict__ cs_cur,
    float* __restrict__ cs_next)
{
    int b, rc;
    decode_pair_bid(blockIdx.x, b, rc);
    const int t = threadIdx.x;
    if (t < 64) cs_next[(b << 10) + (rc << 6) + t] = 0.f;

    const int nr = nrows[b];
    const int r0 = rc << 5;
    if (r0 >= nr) return;
    const int nc = ncols[b];

    __shared__ __half e_lds[RCH * 1024];
    __shared__ float a_lds[RCH];

    const int wave = t >> 6;
    const int lane = t & 63;
    const int cbase = lane << 4;
    const bool cOK = cbase < nc;

    float wgt[16];
    if (cOK) {
        const float* __restrict__ csp = cs_prev + (b << 10) + cbase;
        #pragma unroll
        for (int q = 0; q < 4; ++q) {
            const float4 c4v = *reinterpret_cast<const float4*>(csp + (q << 2));
            wgt[4*q+0] = (cbase + 4*q + 0 < nc) ? fast_rcp(c4v.x) : 0.f;
            wgt[4*q+1] = (cbase + 4*q + 1 < nc) ? fast_rcp(c4v.y) : 0.f;
            wgt[4*q+2] = (cbase + 4*q + 2 < nc) ? fast_rcp(c4v.z) : 0.f;
            wgt[4*q+3] = (cbase + 4*q + 3 < nc) ? fast_rcp(c4v.w) : 0.f;
        }
    }

    #pragma unroll 1
    for (int k = 0; k < 4; ++k) {
        const int rr = (wave << 2) + k;
        const int r = r0 + rr;
        float s0 = 0.f, s1 = 0.f;
        float4 p0, p1;
        if (r < nr && cOK) {
            const __half* __restrict__ erow =
                E + ((size_t)b << 19) + ((size_t)r << 10) + cbase;
            p0 = *reinterpret_cast<const float4*>(erow);
            p1 = *reinterpret_cast<const float4*>(erow + 8);
            const __half2* h0 = reinterpret_cast<const __half2*>(&p0);
            const __half2* h1 = reinterpret_cast<const __half2*>(&p1);
            #pragma unroll
            for (int q = 0; q < 4; ++q) {
                const float2 f = __half22float2(h0[q]);
                s0 = fmaf(f.x, wgt[2*q], s0);
                s1 = fmaf(f.y, wgt[2*q+1], s1);
            }
            #pragma unroll
            for (int q = 0; q < 4; ++q) {
                const float2 f = __half22float2(h1[q]);
                s0 = fmaf(f.x, wgt[8+2*q], s0);
                s1 = fmaf(f.y, wgt[8+2*q+1], s1);
            }
        } else {
            p0 = make_float4(0.f, 0.f, 0.f, 0.f);
            p1 = p0;
        }
        __half* dst = e_lds + (rr << 10) + cbase;
        *reinterpret_cast<float4*>(dst)     = p0;
        *reinterpret_cast<float4*>(dst + 8) = p1;
        const float sum = wave_sum(s0 + s1);
        if (lane == 0) a_lds[rr] = (r < nr) ? 1.0f / sum : 0.f;
    }
    __syncthreads();
    if (t < RCH) a[(b << 9) + r0 + t] = a_lds[t];

    phase2_col(e_lds, a_lds, b, nc, t, cs_cur);
}

__global__ __launch_bounds__(256) void out_step_f(
    const __half* __restrict__ E, const int* __restrict__ nrows,
    const int* __restrict__ ncols, const float* __restrict__ a,
    const float* __restrict__ cs, float* __restrict__ out)
{
    const int bid = blockIdx.x;
    const int xcd = bid & 7;
    const int j = bid >> 3;
    const int r = j & 1023;
    const int b = (xcd << 3) | (j >> 10);
    const int c0 = threadIdx.x << 2;

    const int nr = nrows[b];
    const int nc = ncols[b];
    float4 o = make_float4(0.f, 0.f, 0.f, 0.f);
    if (r < nr && c0 < nc) {
        const float ar = a[(b << 9) + r];
        float2 pk = *reinterpret_cast<const float2*>(
            E + ((size_t)b << 19) + ((size_t)r << 10) + c0);
        const float2 f01 = __half22float2(reinterpret_cast<const __half2*>(&pk)[0]);
        const float2 f23 = __half22float2(reinterpret_cast<const __half2*>(&pk)[1]);
        const float4 c4v = *reinterpret_cast<const float4*>(cs + (b << 10) + c0);
        o.x = f01.x * ar * fast_rcp(c4v.x);
        o.y = (c0 + 1 < nc) ? f01.y * ar * fast_rcp(c4v.y) : 0.f;
        o.z = (c0 + 2 < nc) ? f23.x * ar * fast_rcp(c4v.z) : 0.f;
        o.w = (c0 + 3 < nc) ? f23.y * ar * fast_rcp(c4v.w) : 0.f;
    }
    *reinterpret_cast<float4*>(out + ((size_t)b << 20) + ((size_t)r << 10) + c0) = o;
}

// ============================================================================

extern "C" void kernel_launch(void* const* d_in, const int* in_sizes, int n_in,
                              void* d_out, int out_size, void* d_ws, size_t ws_size,
                              hipStream_t stream) {
    const float* s = (const float*)d_in[0];
    const int* nrows = (const int*)d_in[1];
    const int* ncols = (const int*)d_in[2];
    float* out = (float*)d_out;

    const size_t CS_ELEMS = (size_t)B_DIM * 1024;   // 65536

    // --- primary: cooperative single kernel (needs 768 KiB ws) ---
    bool coop_done = false;
    if (ws_size >= 3 * CS_ELEMS * sizeof(float)) {
        float* cs0 = (float*)d_ws;
        float* cs1 = cs0 + CS_ELEMS;
        float* cs2 = cs1 + CS_ELEMS;
        hipMemsetAsync(cs0, 0, CS_ELEMS * sizeof(float), stream);
        void* args[] = {(void*)&s, (void*)&nrows, (void*)&ncols,
                        (void*)&cs0, (void*)&cs1, (void*)&cs2, (void*)&out};
        hipError_t err = hipLaunchCooperativeKernel(
            reinterpret_cast<const void*>(sinkhorn_coop),
            dim3(512), dim3(512), args, 0, stream);
        coop_done = (err == hipSuccess);
        if (!coop_done) (void)hipGetLastError();   // clear sticky error
    }
    if (coop_done) return;

    // --- fallback: round-7 kernel sequence (needs ~65 MiB ws) ---
    const size_t E_BYTES = (size_t)B_DIM * 512 * 1024 * 2;
    float* cs0f;
    {
        __half* E = (__half*)d_ws;
        float* a = (float*)((char*)d_ws + E_BYTES);
        float* cs0 = a + B_DIM * 512;
        float* cs1 = cs0 + CS_ELEMS;
        float* cs2 = cs1 + CS_ELEMS;
        cs0f = cs0;

        hipMemsetAsync(cs0, 0, CS_ELEMS * sizeof(float), stream);

        const int nblk = 16 * B_DIM;
        pair_first<<<nblk, 512, 0, stream>>>(s, nrows, ncols, E, a, cs0, cs1);
        pair_mid<<<nblk, 512, 0, stream>>>(E, nrows, ncols, cs0, a, cs1, cs2);
        pair_mid<<<nblk, 512, 0, stream>>>(E, nrows, ncols, cs1, a, cs2, cs0);
        pair_mid<<<nblk, 512, 0, stream>>>(E, nrows, ncols, cs2, a, cs0, cs1);
        pair_mid<<<nblk, 512, 0, stream>>>(E, nrows, ncols, cs0, a, cs1, cs2);
        out_step_f<<<65536, 256, 0, stream>>>(E, nrows, ncols, a, cs1, out);
    }
    (void)cs0f;
}

// Round 9
// 553.787 us; speedup vs baseline: 1.0418x; 1.0418x over previous
//
#include <hip/hip_runtime.h>
#include <hip/hip_fp16.h>
#include <hip/hip_cooperative_groups.h>

namespace cg = cooperative_groups;

#define B_DIM 64

__device__ __forceinline__ float fast_rcp(float x) {
#if __has_builtin(__builtin_amdgcn_rcpf)
    return __builtin_amdgcn_rcpf(x);
#else
    return 1.0f / x;
#endif
}

__device__ __forceinline__ float wave_sum(float x) {
    #pragma unroll
    for (int off = 1; off < 64; off <<= 1) x += __shfl_xor(x, off);
    return x;
}

// ================= cooperative single-kernel path =================
// Sinkhorn, linear space. E = exp(s) lives ENTIRELY in VGPRs.
// grid 512 x 256 threads, __launch_bounds__(256,2): VGPR cap 256,
// 2 blocks/CU co-resident (= exactly the coop requirement).
// Block g: batch b = g>>3, row slice half = g&7 -> rows [half*64, +64).
// Wave w (of 4) owns rows rbase = half*64 + w*16 + k, k=0..15.
// Lane l owns cols {j*256 + 4l..+3, j=0..3} (float4-coalesced everywhere).
// Per thread: 16 rows x 16 cols = 256 E elems packed fp16 in EA[16],EB[16]
// (32 float4 = 128 VGPRs). NO lambdas - phases are macros so all array
// indices are compile-time constants after unroll (rule: runtime-indexed /
// lambda-captured arrays demote to scratch; round-8 proved it at 452 MB).
// 5 epochs {row-step from regs; col partials -> LDS[4][1024] -> atomics}
// separated by grid.sync(); cs0/1/2 rotate, zeroed one epoch ahead.
// out = E * a[r] / cs_final[c] from regs; rows 512.. zero-filled early.

#define COL_PHASE(CSCUR)                                                      \
  do {                                                                        \
    float4 p0 = make_float4(0.f, 0.f, 0.f, 0.f), p1 = p0, p2 = p0, p3 = p0;   \
    _Pragma("unroll")                                                         \
    for (int k = 0; k < 16; ++k) {                                            \
      const float av = aR[k];                                                 \
      const __half2* hA = reinterpret_cast<const __half2*>(&EA[k]);           \
      const __half2* hB = reinterpret_cast<const __half2*>(&EB[k]);           \
      float2 f;                                                               \
      f = __half22float2(hA[0]); p0.x = fmaf(f.x, av, p0.x); p0.y = fmaf(f.y, av, p0.y); \
      f = __half22float2(hA[1]); p0.z = fmaf(f.x, av, p0.z); p0.w = fmaf(f.y, av, p0.w); \
      f = __half22float2(hA[2]); p1.x = fmaf(f.x, av, p1.x); p1.y = fmaf(f.y, av, p1.y); \
      f = __half22float2(hA[3]); p1.z = fmaf(f.x, av, p1.z); p1.w = fmaf(f.y, av, p1.w); \
      f = __half22float2(hB[0]); p2.x = fmaf(f.x, av, p2.x); p2.y = fmaf(f.y, av, p2.y); \
      f = __half22float2(hB[1]); p2.z = fmaf(f.x, av, p2.z); p2.w = fmaf(f.y, av, p2.w); \
      f = __half22float2(hB[2]); p3.x = fmaf(f.x, av, p3.x); p3.y = fmaf(f.y, av, p3.y); \
      f = __half22float2(hB[3]); p3.z = fmaf(f.x, av, p3.z); p3.w = fmaf(f.y, av, p3.w); \
    }                                                                         \
    *reinterpret_cast<float4*>(cls + (w << 10) + c4)       = p0;              \
    *reinterpret_cast<float4*>(cls + (w << 10) + 256 + c4) = p1;              \
    *reinterpret_cast<float4*>(cls + (w << 10) + 512 + c4) = p2;              \
    *reinterpret_cast<float4*>(cls + (w << 10) + 768 + c4) = p3;              \
    __syncthreads();                                                          \
    {                                                                         \
      float* __restrict__ cur = (CSCUR) + (b << 10);                          \
      _Pragma("unroll")                                                       \
      for (int hh = 0; hh < 4; ++hh) {                                        \
        const int c = t + (hh << 8);                                          \
        const float v = cls[c] + cls[1024 + c] + cls[2048 + c] + cls[3072 + c]; \
        if (v != 0.f) atomicAdd(cur + c, v);                                  \
      }                                                                       \
    }                                                                         \
    __syncthreads();                                                          \
  } while (0)

#define LOAD_WV(CSPREV)                                                       \
  do {                                                                        \
    const float* __restrict__ csb = (CSPREV) + (b << 10);                     \
    const float4 v0 = *reinterpret_cast<const float4*>(csb + c4);             \
    wv0.x = fast_rcp(v0.x); wv0.y = fast_rcp(v0.y);                           \
    wv0.z = fast_rcp(v0.z); wv0.w = fast_rcp(v0.w);                           \
    const float4 v1 = *reinterpret_cast<const float4*>(csb + 256 + c4);       \
    wv1.x = fast_rcp(v1.x); wv1.y = fast_rcp(v1.y);                           \
    wv1.z = fast_rcp(v1.z); wv1.w = fast_rcp(v1.w);                           \
    const int c2 = 512 + c4;                                                  \
    if (c2 < nc) {                                                            \
      const float4 v2 = *reinterpret_cast<const float4*>(csb + c2);           \
      wv2.x = fast_rcp(v2.x);                                                 \
      wv2.y = (c2 + 1 < nc) ? fast_rcp(v2.y) : 0.f;                           \
      wv2.z = (c2 + 2 < nc) ? fast_rcp(v2.z) : 0.f;                           \
      wv2.w = (c2 + 3 < nc) ? fast_rcp(v2.w) : 0.f;                           \
    } else { wv2 = make_float4(0.f, 0.f, 0.f, 0.f); }                         \
    const int c3 = 768 + c4;                                                  \
    if (c3 < nc) {                                                            \
      const float4 v3 = *reinterpret_cast<const float4*>(csb + c3);           \
      wv3.x = fast_rcp(v3.x);                                                 \
      wv3.y = (c3 + 1 < nc) ? fast_rcp(v3.y) : 0.f;                           \
      wv3.z = (c3 + 2 < nc) ? fast_rcp(v3.z) : 0.f;                           \
      wv3.w = (c3 + 3 < nc) ? fast_rcp(v3.w) : 0.f;                           \
    } else { wv3 = make_float4(0.f, 0.f, 0.f, 0.f); }                         \
  } while (0)

#define ROW_PHASE(CSPREV)                                                     \
  do {                                                                        \
    float4 wv0, wv1, wv2, wv3;                                                \
    LOAD_WV(CSPREV);                                                          \
    _Pragma("unroll")                                                         \
    for (int k = 0; k < 16; ++k) {                                            \
      const __half2* hA = reinterpret_cast<const __half2*>(&EA[k]);           \
      const __half2* hB = reinterpret_cast<const __half2*>(&EB[k]);           \
      float2 f; float a0, a1;                                                 \
      f = __half22float2(hA[0]); a0 = f.x * wv0.x;          a1 = f.y * wv0.y; \
      f = __half22float2(hA[1]); a0 = fmaf(f.x, wv0.z, a0); a1 = fmaf(f.y, wv0.w, a1); \
      f = __half22float2(hA[2]); a0 = fmaf(f.x, wv1.x, a0); a1 = fmaf(f.y, wv1.y, a1); \
      f = __half22float2(hA[3]); a0 = fmaf(f.x, wv1.z, a0); a1 = fmaf(f.y, wv1.w, a1); \
      f = __half22float2(hB[0]); a0 = fmaf(f.x, wv2.x, a0); a1 = fmaf(f.y, wv2.y, a1); \
      f = __half22float2(hB[1]); a0 = fmaf(f.x, wv2.z, a0); a1 = fmaf(f.y, wv2.w, a1); \
      f = __half22float2(hB[2]); a0 = fmaf(f.x, wv3.x, a0); a1 = fmaf(f.y, wv3.y, a1); \
      f = __half22float2(hB[3]); a0 = fmaf(f.x, wv3.z, a0); a1 = fmaf(f.y, wv3.w, a1); \
      const float sum = wave_sum(a0 + a1);                                    \
      aR[k] = (rbase + k < nr) ? fast_rcp(sum) : 0.f;                         \
    }                                                                         \
  } while (0)

__global__ __launch_bounds__(256, 2) void sinkhorn_coop(
    const float* __restrict__ s, const int* __restrict__ nrows,
    const int* __restrict__ ncols, float* __restrict__ cs0,
    float* __restrict__ cs1, float* __restrict__ cs2,
    float* __restrict__ out)
{
    cg::grid_group grid = cg::this_grid();
    __shared__ float cls[4 * 1024];   // 16 KiB

    const int g = blockIdx.x;
    const int b = g >> 3;
    const int half = g & 7;
    const int t = threadIdx.x;
    const int w = t >> 6;
    const int l = t & 63;
    const int c4 = l << 2;
    const int nr = nrows[b];
    const int nc = ncols[b];
    const int rbase = (half << 6) + (w << 4);

    float4 EA[16], EB[16];   // 128 VGPRs of packed fp16 E
    float aR[16];

    // zero cs1 (epoch-1 target); cs0 pre-zeroed by host memset.
    if (t < 128) cs1[(b << 10) + (half << 7) + t] = 0.f;

    // ---- epoch 0 row step: load s, exp, pack, row sums (weights = 1) ----
    #pragma unroll
    for (int k = 0; k < 16; ++k) {
        const int r = rbase + k;
        float e[16];
        if (r < nr) {   // wave-uniform
            const float* __restrict__ srow =
                s + ((size_t)b << 20) + ((size_t)r << 10);
            const float4 x0 = *reinterpret_cast<const float4*>(srow + c4);
            const float4 x1 = *reinterpret_cast<const float4*>(srow + 256 + c4);
            e[0] = __expf(x0.x); e[1] = __expf(x0.y);
            e[2] = __expf(x0.z); e[3] = __expf(x0.w);
            e[4] = __expf(x1.x); e[5] = __expf(x1.y);
            e[6] = __expf(x1.z); e[7] = __expf(x1.w);
            const int c2 = 512 + c4;
            if (c2 < nc) {
                const float4 x2 = *reinterpret_cast<const float4*>(srow + c2);
                e[8]  = __expf(x2.x);
                e[9]  = (c2 + 1 < nc) ? __expf(x2.y) : 0.f;
                e[10] = (c2 + 2 < nc) ? __expf(x2.z) : 0.f;
                e[11] = (c2 + 3 < nc) ? __expf(x2.w) : 0.f;
            } else { e[8] = 0.f; e[9] = 0.f; e[10] = 0.f; e[11] = 0.f; }
            const int c3 = 768 + c4;
            if (c3 < nc) {
                const float4 x3 = *reinterpret_cast<const float4*>(srow + c3);
                e[12] = __expf(x3.x);
                e[13] = (c3 + 1 < nc) ? __expf(x3.y) : 0.f;
                e[14] = (c3 + 2 < nc) ? __expf(x3.z) : 0.f;
                e[15] = (c3 + 3 < nc) ? __expf(x3.w) : 0.f;
            } else { e[12] = 0.f; e[13] = 0.f; e[14] = 0.f; e[15] = 0.f; }
        } else {
            #pragma unroll
            for (int i = 0; i < 16; ++i) e[i] = 0.f;
        }
        __half2 h[8];
        #pragma unroll
        for (int q = 0; q < 8; ++q)
            h[q] = __floats2half2_rn(e[2 * q], e[2 * q + 1]);
        EA[k] = *reinterpret_cast<const float4*>(&h[0]);
        EB[k] = *reinterpret_cast<const float4*>(&h[4]);
        float acc = ((e[0] + e[1]) + (e[2] + e[3])) + ((e[4] + e[5]) + (e[6] + e[7]))
                  + ((e[8] + e[9]) + (e[10] + e[11])) + ((e[12] + e[13]) + (e[14] + e[15]));
        acc = wave_sum(acc);
        aR[k] = (r < nr) ? fast_rcp(acc) : 0.f;
    }

    // zero-fill out rows 512..1023 for this (b, half) slice (overlaps compute)
    {
        const float4 z = make_float4(0.f, 0.f, 0.f, 0.f);
        float4* __restrict__ zb = reinterpret_cast<float4*>(
            out + ((size_t)b << 20) + ((size_t)(512 + (half << 6)) << 10));
        #pragma unroll 4
        for (int i = t; i < 64 * 256; i += 256) zb[i] = z;
    }

    COL_PHASE(cs0);  grid.sync();                               // epoch 0
    if (t < 128) cs2[(b << 10) + (half << 7) + t] = 0.f;        // for epoch 2
    ROW_PHASE(cs0);  COL_PHASE(cs1);  grid.sync();              // epoch 1
    if (t < 128) cs0[(b << 10) + (half << 7) + t] = 0.f;        // for epoch 3
    ROW_PHASE(cs1);  COL_PHASE(cs2);  grid.sync();              // epoch 2
    if (t < 128) cs1[(b << 10) + (half << 7) + t] = 0.f;        // for epoch 4
    ROW_PHASE(cs2);  COL_PHASE(cs0);  grid.sync();              // epoch 3
    ROW_PHASE(cs0);  COL_PHASE(cs1);  grid.sync();              // epoch 4

    // ---- output: out = E * a[r] * (1/cs1[c]) straight from registers ----
    {
        float4 wv0, wv1, wv2, wv3;
        LOAD_WV(cs1);
        #pragma unroll
        for (int k = 0; k < 16; ++k) {
            const int r = rbase + k;
            const float av = aR[k];   // 0 for r >= nr -> zeros
            float* __restrict__ orow =
                out + ((size_t)b << 20) + ((size_t)r << 10);
            const __half2* hA = reinterpret_cast<const __half2*>(&EA[k]);
            const __half2* hB = reinterpret_cast<const __half2*>(&EB[k]);
            float2 fa, fb;
            float4 o;
            fa = __half22float2(hA[0]); fb = __half22float2(hA[1]);
            o = make_float4(fa.x * av * wv0.x, fa.y * av * wv0.y,
                            fb.x * av * wv0.z, fb.y * av * wv0.w);
            *reinterpret_cast<float4*>(orow + c4) = o;
            fa = __half22float2(hA[2]); fb = __half22float2(hA[3]);
            o = make_float4(fa.x * av * wv1.x, fa.y * av * wv1.y,
                            fb.x * av * wv1.z, fb.y * av * wv1.w);
            *reinterpret_cast<float4*>(orow + 256 + c4) = o;
            fa = __half22float2(hB[0]); fb = __half22float2(hB[1]);
            o = make_float4(fa.x * av * wv2.x, fa.y * av * wv2.y,
                            fb.x * av * wv2.z, fb.y * av * wv2.w);
            *reinterpret_cast<float4*>(orow + 512 + c4) = o;
            fa = __half22float2(hB[2]); fb = __half22float2(hB[3]);
            o = make_float4(fa.x * av * wv3.x, fa.y * av * wv3.y,
                            fb.x * av * wv3.z, fb.y * av * wv3.w);
            *reinterpret_cast<float4*>(orow + 768 + c4) = o;
        }
    }
}

// ==================== round-7 fallback (coop launch failure) ===============

#define RCH 32

__device__ __forceinline__ void phase2_col(
    const __half* __restrict__ e_lds, const float* __restrict__ a_lds,
    int b, int nc, int t, float* __restrict__ cs_cur)
{
    const int c0 = t << 1;
    if (c0 >= nc) return;
    float s0 = 0.f, s1 = 0.f;
    #pragma unroll
    for (int rr = 0; rr < RCH; ++rr) {
        const float2 f = __half22float2(
            *reinterpret_cast<const __half2*>(e_lds + (rr << 10) + c0));
        const float av = a_lds[rr];
        s0 = fmaf(f.x, av, s0);
        s1 = fmaf(f.y, av, s1);
    }
    if (s0 != 0.f) atomicAdd(cs_cur + (b << 10) + c0, s0);
    if (s1 != 0.f) atomicAdd(cs_cur + (b << 10) + c0 + 1, s1);
}

__device__ __forceinline__ void decode_pair_bid(int bid, int& b, int& rc) {
    const int xcd = bid & 7;
    const int j = bid >> 3;
    rc = j & 15;
    b = (xcd << 3) | (j >> 4);
}

__global__ __launch_bounds__(512) void pair_first(
    const float* __restrict__ s, const int* __restrict__ nrows,
    const int* __restrict__ ncols, __half* __restrict__ E,
    float* __restrict__ a, float* __restrict__ cs_cur,
    float* __restrict__ cs_next)
{
    int b, rc;
    decode_pair_bid(blockIdx.x, b, rc);
    const int t = threadIdx.x;
    if (t < 64) cs_next[(b << 10) + (rc << 6) + t] = 0.f;

    const int nr = nrows[b];
    const int r0 = rc << 5;
    if (r0 >= nr) return;
    const int nc = ncols[b];

    __shared__ __half e_lds[RCH * 1024];
    __shared__ float a_lds[RCH];

    const int wave = t >> 6;
    const int lane = t & 63;
    const int cbase = lane << 4;
    const bool cOK = cbase < nc;

    #pragma unroll 1
    for (int k = 0; k < 4; ++k) {
        const int rr = (wave << 2) + k;
        const int r = r0 + rr;
        float sum = 0.f;
        __half2 h[8];
        if (r < nr && cOK) {
            const float* __restrict__ srow =
                s + ((size_t)b << 20) + ((size_t)r << 10) + cbase;
            float e[16];
            #pragma unroll
            for (int q = 0; q < 4; ++q) {
                const float4 x = *reinterpret_cast<const float4*>(srow + (q << 2));
                e[4*q+0] = __expf(x.x); e[4*q+1] = __expf(x.y);
                e[4*q+2] = __expf(x.z); e[4*q+3] = __expf(x.w);
            }
            #pragma unroll
            for (int j = 0; j < 16; ++j)
                if (cbase + j >= nc) e[j] = 0.f;
            #pragma unroll
            for (int q = 0; q < 8; ++q)
                h[q] = __floats2half2_rn(e[2*q], e[2*q+1]);
            __half* __restrict__ erow =
                E + ((size_t)b << 19) + ((size_t)r << 10) + cbase;
            *reinterpret_cast<float4*>(erow)     = *reinterpret_cast<const float4*>(&h[0]);
            *reinterpret_cast<float4*>(erow + 8) = *reinterpret_cast<const float4*>(&h[4]);
            #pragma unroll
            for (int j = 0; j < 16; ++j) sum += e[j];
        } else {
            #pragma unroll
            for (int q = 0; q < 8; ++q) h[q] = __floats2half2_rn(0.f, 0.f);
        }
        __half* dst = e_lds + (rr << 10) + cbase;
        *reinterpret_cast<float4*>(dst)     = *reinterpret_cast<const float4*>(&h[0]);
        *reinterpret_cast<float4*>(dst + 8) = *reinterpret_cast<const float4*>(&h[4]);
        sum = wave_sum(sum);
        if (lane == 0) a_lds[rr] = (r < nr) ? 1.0f / sum : 0.f;
    }
    __syncthreads();
    if (t < RCH) a[(b << 9) + r0 + t] = a_lds[t];

    phase2_col(e_lds, a_lds, b, nc, t, cs_cur);
}

__global__ __launch_bounds__(512) void pair_mid(
    const __half* __restrict__ E, const int* __restrict__ nrows,
    const int* __restrict__ ncols, const float* __restrict__ cs_prev,
    float* __restrict__ a, float* __restrict__ cs_cur,
    float* __restrict__ cs_next)
{
    int b, rc;
    decode_pair_bid(blockIdx.x, b, rc);
    const int t = threadIdx.x;
    if (t < 64) cs_next[(b << 10) + (rc << 6) + t] = 0.f;

    const int nr = nrows[b];
    const int r0 = rc << 5;
    if (r0 >= nr) return;
    const int nc = ncols[b];

    __shared__ __half e_lds[RCH * 1024];
    __shared__ float a_lds[RCH];

    const int wave = t >> 6;
    const int lane = t & 63;
    const int cbase = lane << 4;
    const bool cOK = cbase < nc;

    float wgt[16];
    if (cOK) {
        const float* __restrict__ csp = cs_prev + (b << 10) + cbase;
        #pragma unroll
        for (int q = 0; q < 4; ++q) {
            const float4 c4v = *reinterpret_cast<const float4*>(csp + (q << 2));
            wgt[4*q+0] = (cbase + 4*q + 0 < nc) ? fast_rcp(c4v.x) : 0.f;
            wgt[4*q+1] = (cbase + 4*q + 1 < nc) ? fast_rcp(c4v.y) : 0.f;
            wgt[4*q+2] = (cbase + 4*q + 2 < nc) ? fast_rcp(c4v.z) : 0.f;
            wgt[4*q+3] = (cbase + 4*q + 3 < nc) ? fast_rcp(c4v.w) : 0.f;
        }
    }

    #pragma unroll 1
    for (int k = 0; k < 4; ++k) {
        const int rr = (wave << 2) + k;
        const int r = r0 + rr;
        float s0 = 0.f, s1 = 0.f;
        float4 p0, p1;
        if (r < nr && cOK) {
            const __half* __restrict__ erow =
                E + ((size_t)b << 19) + ((size_t)r << 10) + cbase;
            p0 = *reinterpret_cast<const float4*>(erow);
            p1 = *reinterpret_cast<const float4*>(erow + 8);
            const __half2* h0 = reinterpret_cast<const __half2*>(&p0);
            const __half2* h1 = reinterpret_cast<const __half2*>(&p1);
            #pragma unroll
            for (int q = 0; q < 4; ++q) {
                const float2 f = __half22float2(h0[q]);
                s0 = fmaf(f.x, wgt[2*q], s0);
                s1 = fmaf(f.y, wgt[2*q+1], s1);
            }
            #pragma unroll
            for (int q = 0; q < 4; ++q) {
                const float2 f = __half22float2(h1[q]);
                s0 = fmaf(f.x, wgt[8+2*q], s0);
                s1 = fmaf(f.y, wgt[8+2*q+1], s1);
            }
        } else {
            p0 = make_float4(0.f, 0.f, 0.f, 0.f);
            p1 = p0;
        }
        __half* dst = e_lds + (rr << 10) + cbase;
        *reinterpret_cast<float4*>(dst)     = p0;
        *reinterpret_cast<float4*>(dst + 8) = p1;
        const float sum = wave_sum(s0 + s1);
        if (lane == 0) a_lds[rr] = (r < nr) ? 1.0f / sum : 0.f;
    }
    __syncthreads();
    if (t < RCH) a[(b << 9) + r0 + t] = a_lds[t];

    phase2_col(e_lds, a_lds, b, nc, t, cs_cur);
}

__global__ __launch_bounds__(256) void out_step_f(
    const __half* __restrict__ E, const int* __restrict__ nrows,
    const int* __restrict__ ncols, const float* __restrict__ a,
    const float* __restrict__ cs, float* __restrict__ out)
{
    const int bid = blockIdx.x;
    const int xcd = bid & 7;
    const int j = bid >> 3;
    const int r = j & 1023;
    const int b = (xcd << 3) | (j >> 10);
    const int c0 = threadIdx.x << 2;

    const int nr = nrows[b];
    const int nc = ncols[b];
    float4 o = make_float4(0.f, 0.f, 0.f, 0.f);
    if (r < nr && c0 < nc) {
        const float ar = a[(b << 9) + r];
        float2 pk = *reinterpret_cast<const float2*>(
            E + ((size_t)b << 19) + ((size_t)r << 10) + c0);
        const float2 f01 = __half22float2(reinterpret_cast<const __half2*>(&pk)[0]);
        const float2 f23 = __half22float2(reinterpret_cast<const __half2*>(&pk)[1]);
        const float4 c4v = *reinterpret_cast<const float4*>(cs + (b << 10) + c0);
        o.x = f01.x * ar * fast_rcp(c4v.x);
        o.y = (c0 + 1 < nc) ? f01.y * ar * fast_rcp(c4v.y) : 0.f;
        o.z = (c0 + 2 < nc) ? f23.x * ar * fast_rcp(c4v.z) : 0.f;
        o.w = (c0 + 3 < nc) ? f23.y * ar * fast_rcp(c4v.w) : 0.f;
    }
    *reinterpret_cast<float4*>(out + ((size_t)b << 20) + ((size_t)r << 10) + c0) = o;
}

// ============================================================================

extern "C" void kernel_launch(void* const* d_in, const int* in_sizes, int n_in,
                              void* d_out, int out_size, void* d_ws, size_t ws_size,
                              hipStream_t stream) {
    const float* s = (const float*)d_in[0];
    const int* nrows = (const int*)d_in[1];
    const int* ncols = (const int*)d_in[2];
    float* out = (float*)d_out;

    const size_t CS_ELEMS = (size_t)B_DIM * 1024;   // 65536

    // --- primary: cooperative single kernel (needs 768 KiB ws) ---
    bool coop_done = false;
    if (ws_size >= 3 * CS_ELEMS * sizeof(float)) {
        float* cs0 = (float*)d_ws;
        float* cs1 = cs0 + CS_ELEMS;
        float* cs2 = cs1 + CS_ELEMS;
        hipMemsetAsync(cs0, 0, CS_ELEMS * sizeof(float), stream);
        void* args[] = {(void*)&s, (void*)&nrows, (void*)&ncols,
                        (void*)&cs0, (void*)&cs1, (void*)&cs2, (void*)&out};
        hipError_t err = hipLaunchCooperativeKernel(
            reinterpret_cast<const void*>(sinkhorn_coop),
            dim3(512), dim3(256), args, 0, stream);
        coop_done = (err == hipSuccess);
        if (!coop_done) (void)hipGetLastError();   // clear sticky error
    }
    if (coop_done) return;

    // --- fallback: round-7 kernel sequence (needs ~65 MiB ws) ---
    const size_t E_BYTES = (size_t)B_DIM * 512 * 1024 * 2;
    {
        __half* E = (__half*)d_ws;
        float* a = (float*)((char*)d_ws + E_BYTES);
        float* cs0 = a + B_DIM * 512;
        float* cs1 = cs0 + CS_ELEMS;
        float* cs2 = cs1 + CS_ELEMS;

        hipMemsetAsync(cs0, 0, CS_ELEMS * sizeof(float), stream);

        const int nblk = 16 * B_DIM;
        pair_first<<<nblk, 512, 0, stream>>>(s, nrows, ncols, E, a, cs0, cs1);
        pair_mid<<<nblk, 512, 0, stream>>>(E, nrows, ncols, cs0, a, cs1, cs2);
        pair_mid<<<nblk, 512, 0, stream>>>(E, nrows, ncols, cs1, a, cs2, cs0);
        pair_mid<<<nblk, 512, 0, stream>>>(E, nrows, ncols, cs2, a, cs0, cs1);
        pair_mid<<<nblk, 512, 0, stream>>>(E, nrows, ncols, cs0, a, cs1, cs2);
        out_step_f<<<65536, 256, 0, stream>>>(E, nrows, ncols, a, cs1, out);
    }
}